// Round 3
// baseline (254.981 us; speedup 1.0000x reference)
//
#include <hip/hip_runtime.h>
#include <hip/hip_bf16.h>

#define BIG 3.4e38f

// ---------- top-5 helpers ----------

// Merge two ascending sorted 5-lists, keep the 5 smallest in a[].
__device__ __forceinline__ void merge5(float a[5], const float* b) {
    float r[5];
#pragma unroll
    for (int k = 0; k < 5; ++k) {
        float best = BIG;
#pragma unroll
        for (int i = 0; i <= k + 1; ++i) {
            const int j = k + 1 - i;
            float va = (i == 0) ? -BIG : a[i - 1];
            float vb = (j == 0) ? -BIG : b[j - 1];
            best = fminf(best, fmaxf(va, vb));
        }
        r[k] = best;
    }
#pragma unroll
    for (int k = 0; k < 5; ++k) a[k] = r[k];
}

__device__ __forceinline__ void top5_insert(float m[5], float d) {
    if (d < m[4]) {
        m[4] = d;
#pragma unroll
        for (int k = 4; k > 0; --k) {
            float lo = fminf(m[k - 1], m[k]);
            float hi = fmaxf(m[k - 1], m[k]);
            m[k - 1] = lo;
            m[k] = hi;
        }
    }
}

// 5 smallest across the wave via iterative min-extract (~85 VALU ops vs
// 270 for the merge network). Exact w.r.t. duplicates: ballot+ffs masks
// exactly one instance per extraction. Result (sorted) in all lanes.
__device__ __forceinline__ void wave_top5_extract(float d, int lane,
                                                  float r[5]) {
#pragma unroll
    for (int k = 0; k < 5; ++k) {
        float v = d;
#pragma unroll
        for (int off = 32; off >= 1; off >>= 1)
            v = fminf(v, __shfl_xor(v, off, 64));
        r[k] = v;
        const unsigned long long ball = __ballot(d == v);
        const int src = (int)__ffsll(ball) - 1;
        if (lane == src) d = BIG;
    }
}

__device__ __forceinline__ void wave_merge_top5(float m[5]) {
#pragma unroll
    for (int off = 1; off < 64; off <<= 1) {
        float o[5];
#pragma unroll
        for (int k = 0; k < 5; ++k) o[k] = __shfl_xor(m[k], off, 64);
        merge5(m, o);
    }
}

__device__ __forceinline__ bool block_merge_top5(float m[5], float (*s_top)[5],
                                                 float r[5]) {
    const int wid = threadIdx.x >> 6;
    if ((threadIdx.x & 63) == 0) {
#pragma unroll
        for (int k = 0; k < 5; ++k) s_top[wid][k] = m[k];
    }
    __syncthreads();
    if (threadIdx.x == 0) {
#pragma unroll
        for (int k = 0; k < 5; ++k) r[k] = s_top[0][k];
        merge5(r, s_top[1]);
        merge5(r, s_top[2]);
        merge5(r, s_top[3]);
        return true;
    }
    return false;
}

// ---------- K1 v3: in-wave channel combine, 31.6KB LDS, full residency ----
// Blocks [0,1012): scale-0. Block = (h, col-quarter of 64 positions).
//   Lane = cq*16+pp: 4 channel-quarters x 16 positions per wave; wave wv
//   covers positions wv*16+pp. Per-position partials combine via
//   shfl_xor(16/32) — no LDS exchange, no cross-wave sync in main path.
//   Target table tl is skewed +cq*4 floats so the 4 concurrent b128
//   broadcast groups hit disjoint bank quads (else 4-way conflict).
// Blocks [1012,1076): scale-1 (C=128, ps=1), full dist + block top-5.
__global__ __launch_bounds__(256, 5) void dist_all_kernel(
    const float* __restrict__ src0, const float* __restrict__ tgt0,
    const int* __restrict__ pos0, const float* __restrict__ src1,
    const float* __restrict__ tgt1, const int* __restrict__ pos1,
    float* __restrict__ p2a, float* __restrict__ p2b) {
    __shared__ float tl[7696];        // skewed: t*768 + ch*12 + i*4 + j + cq*4
    __shared__ float s_top[4][10][5];  // per-wave per-target top5

    const int b = blockIdx.x;
    if (b < 1012) {
        // ---- scale 0: C=64, H=W=256, ps=3 ----
        const int h = b >> 2;

        // Gather 10 target patches into skewed LDS layout (23KB of tgt0,
        // L2/L3-resident across the 1012 blocks).
        for (int t = 0; t < 10; ++t) {
            const int th = pos0[2 * t], tw = pos0[2 * t + 1];
            for (int inner = threadIdx.x; inner < 576; inner += 256) {
                const int ch = inner / 9;
                const int rr = inner - ch * 9;
                const int i = rr / 3, j = rr - i * 3;
                tl[t * 768 + ch * 12 + i * 4 + j + ((ch >> 4) << 2)] =
                    tgt0[(size_t)ch * 65536 + (th + i) * 256 + (tw + j)];
            }
        }
        __syncthreads();

        const int lane = threadIdx.x & 63;
        const int wv = threadIdx.x >> 6;  // wave: positions wv*16+pp
        const int pp = lane & 15;
        const int cq = lane >> 4;         // channel quarter
        const int wg = ((b & 3) << 6) + wv * 16 + pp;  // global w
        const int wp = (wg <= 252) ? wg : 252;         // clamp loads

        float acc[10];
#pragma unroll
        for (int t = 0; t < 10; ++t) acc[t] = 0.f;

        const float* sb = src0 + (size_t)(cq * 16) * 65536 + h * 256 + wp;
        const float* tb = tl + cq * 196;  // cq*192 (channels) + cq*4 (skew)
        for (int c = 0; c < 16; ++c) {
            const float* row = sb + (size_t)c * 65536;
            const float* tc = tb + c * 12;
#pragma unroll
            for (int i = 0; i < 3; ++i) {
                const float4 a = *(const float4*)(row + i * 256);
#pragma unroll
                for (int t = 0; t < 10; ++t) {
                    const float4 tv = *(const float4*)(tc + t * 768 + i * 4);
                    acc[t] += fabsf(a.x - tv.x) + fabsf(a.y - tv.y) +
                              fabsf(a.z - tv.z);
                }
            }
        }

        // Combine the 4 channel-quarters (lanes pp, pp+16, pp+32, pp+48).
#pragma unroll
        for (int t = 0; t < 10; ++t) {
            float d = acc[t];
            d += __shfl_xor(d, 16, 64);
            d += __shfl_xor(d, 32, 64);
            acc[t] = d;  // full distance in every lane of the pp-group
        }
        const bool valid = (cq == 0) && (wg < 253);

        // Per-target: wave top-5 of its 16 positions (others masked BIG).
#pragma unroll
        for (int t = 0; t < 10; ++t) {
            float r[5];
            wave_top5_extract(valid ? acc[t] : BIG, lane, r);
            if (lane == 0) {
#pragma unroll
                for (int k = 0; k < 5; ++k) s_top[wv][t][k] = r[k];
            }
        }
        __syncthreads();
        // Block merge: thread t merges the 4 wave lists for target t.
        if (threadIdx.x < 10) {
            const int t = threadIdx.x;
            float r[5];
#pragma unroll
            for (int k = 0; k < 5; ++k) r[k] = s_top[0][t][k];
            merge5(r, s_top[1][t]);
            merge5(r, s_top[2][t]);
            merge5(r, s_top[3][t]);
            float* dst = p2a + (t * 1012 + b) * 5;
#pragma unroll
            for (int k = 0; k < 5; ++k) dst[k] = r[k];
        }
    } else {
        // ---- scale 1: C=128, H=W=128, ps=1 ----
        const int bb = b - 1012;
        for (int idx = threadIdx.x; idx < 640; idx += 256) {
            const int t = idx >> 7, cc = idx & 127;
            tl[idx] =
                tgt1[(size_t)cc * 16384 + pos1[2 * t] * 128 + pos1[2 * t + 1]];
        }
        __syncthreads();

        const int w = threadIdx.x & 127;
        const int h1 = bb * 2 + (threadIdx.x >> 7);  // 0..127
        float acc[5] = {0.f, 0.f, 0.f, 0.f, 0.f};
        const float* sp = src1 + h1 * 128 + w;
        for (int cc = 0; cc < 128; ++cc) {
            const float v = sp[(size_t)cc * 16384];
#pragma unroll
            for (int t = 0; t < 5; ++t) acc[t] += fabsf(v - tl[t * 128 + cc]);
        }
        const int lane = threadIdx.x & 63;
        const int wv = threadIdx.x >> 6;
        const bool valid = (h1 < 127) && (w < 127);
#pragma unroll
        for (int t = 0; t < 5; ++t) {
            float r[5];
            wave_top5_extract(valid ? acc[t] : BIG, lane, r);
            if (lane == 0) {
#pragma unroll
                for (int k = 0; k < 5; ++k) s_top[wv][t][k] = r[k];
            }
        }
        __syncthreads();
        if (threadIdx.x < 5) {
            const int t = threadIdx.x;
            float r[5];
#pragma unroll
            for (int k = 0; k < 5; ++k) r[k] = s_top[0][t][k];
            merge5(r, s_top[1][t]);
            merge5(r, s_top[2][t]);
            merge5(r, s_top[3][t]);
            float* dst = p2b + (t * 64 + bb) * 5;
#pragma unroll
            for (int k = 0; k < 5; ++k) dst[k] = r[k];
        }
    }
}

// ---------- K3: parallel-over-targets final merge + scalar write --------
// Output word: high16 = f32 bits, low16 = RNE bf16 bits (dtype-proof).
__global__ __launch_bounds__(256) void final_merge_kernel(
    const float* __restrict__ p2a, int na,
    const float* __restrict__ p2b, int nb,
    unsigned int* __restrict__ out) {
    __shared__ float s_sum[15];
    const int lane = threadIdx.x & 63;
    const int wv = threadIdx.x >> 6;
#pragma unroll
    for (int rt = 0; rt < 4; ++rt) {
        const int t = wv * 4 + rt;
        if (t < 15) {
            const float* base = (t < 10) ? p2a + t * na : p2b + (t - 10) * nb;
            const int n = (t < 10) ? na : nb;
            const float scale =
                (t < 10) ? 1.f / (576.f * 5.f) : 1.f / (128.f * 5.f);
            float m[5] = {BIG, BIG, BIG, BIG, BIG};
            for (int b0 = 0; b0 < n; b0 += 256) {
                float v[4];
#pragma unroll
                for (int j = 0; j < 4; ++j) {
                    const int idx = b0 + j * 64 + lane;
                    v[j] = (idx < n) ? base[idx] : BIG;
                }
#pragma unroll
                for (int j = 0; j < 4; ++j) top5_insert(m, v[j]);
            }
            wave_merge_top5(m);
            if (lane == 0)
                s_sum[t] = (m[0] + m[1] + m[2] + m[3] + m[4]) * scale;
        }
    }
    __syncthreads();
    if (threadIdx.x == 0) {
        float total = 0.f;
#pragma unroll
        for (int t = 0; t < 15; ++t) total += s_sum[t];
        union { float f; unsigned int i; } uf;
        uf.f = total * 0.1f;
        unsigned int bf = (uf.i + 0x7FFFu + ((uf.i >> 16) & 1u)) >> 16;
        out[0] = (uf.i & 0xFFFF0000u) | (bf & 0xFFFFu);
    }
}

// ---------- fallback (round-2 proven path, tiny ws) ----------
template <int C, int H, int PS, int WM>
__global__ __launch_bounds__(256) void dist_top5_kernel(
    const float* __restrict__ src, const float* __restrict__ tgt,
    const int* __restrict__ pos, float* __restrict__ part) {
    constexpr int W = H;
    constexpr int K = C * PS * PS;
    constexpr int P = WM * WM;
    __shared__ float tlv[K];
    __shared__ float s_top[4][5];
    const int t = blockIdx.y;
    const int th = pos[2 * t], tw = pos[2 * t + 1];
    for (int idx = threadIdx.x; idx < K; idx += 256) {
        int c = idx / (PS * PS);
        int rem = idx - c * PS * PS;
        int i = rem / PS, j = rem - i * PS;
        tlv[idx] = tgt[(c * H + th + i) * W + tw + j];
    }
    __syncthreads();
    const int p = blockIdx.x * 256 + threadIdx.x;
    float d = BIG;
    if (p < P) {
        const int h = p / WM, w = p - h * WM;
        float acc = 0.f;
        for (int c = 0; c < C; ++c)
#pragma unroll
            for (int i = 0; i < PS; ++i) {
                const float* r = src + (c * H + h + i) * W + w;
                const float* tr = &tlv[(c * PS + i) * PS];
#pragma unroll
                for (int j = 0; j < PS; ++j) acc += fabsf(r[j] - tr[j]);
            }
        d = acc;
    }
    float m[5] = {d, BIG, BIG, BIG, BIG};
    wave_merge_top5(m);
    float r[5];
    if (block_merge_top5(m, s_top, r)) {
        float* dst = part + (t * gridDim.x + blockIdx.x) * 5;
#pragma unroll
        for (int k = 0; k < 5; ++k) dst[k] = r[k];
    }
}

extern "C" void kernel_launch(void* const* d_in, const int* in_sizes, int n_in,
                              void* d_out, int out_size, void* d_ws, size_t ws_size,
                              hipStream_t stream) {
    const float* src0 = (const float*)d_in[0];  // [1,64,256,256] f32
    const float* tgt0 = (const float*)d_in[1];
    const float* src1 = (const float*)d_in[2];  // [1,128,128,128] f32
    const float* tgt1 = (const float*)d_in[3];
    const int* pos0 = (const int*)d_in[4];      // [10,2]
    const int* pos1 = (const int*)d_in[5];      // [5,2]
    unsigned int* out = (unsigned int*)d_out;

    constexpr size_t NP2A = 10 * 1012 * 5;  // 50600
    constexpr size_t NP2B = 5 * 64 * 5;     // 1600
    const size_t need = (NP2A + NP2B) * 4;  // ~209 KB

    if (ws_size >= need) {
        float* p2a = (float*)d_ws;
        float* p2b = p2a + NP2A;

        // K1: scale-0 (1012 blocks) + scale-1 (64 blocks), all co-resident.
        dist_all_kernel<<<dim3(1076), 256, 0, stream>>>(
            src0, tgt0, pos0, src1, tgt1, pos1, p2a, p2b);
        // K3: final merge (10 x 5060 values + 5 x 320 values).
        final_merge_kernel<<<dim3(1), 256, 0, stream>>>(
            p2a, 1012 * 5, p2b, 320, out);
    } else {
        // Fallback: round-2 proven path (~57KB of ws).
        float* part0 = (float*)d_ws;
        float* part1 = part0 + 10 * 251 * 5;
        dist_top5_kernel<64, 256, 3, 253>
            <<<dim3(251, 10), 256, 0, stream>>>(src0, tgt0, pos0, part0);
        dist_top5_kernel<128, 128, 1, 127>
            <<<dim3(64, 5), 256, 0, stream>>>(src1, tgt1, pos1, part1);
        final_merge_kernel<<<dim3(1), 256, 0, stream>>>(part0, 1255, part1, 320, out);
    }
}

// Round 4
// 208.472 us; speedup vs baseline: 1.2231x; 1.2231x over previous
//
#include <hip/hip_runtime.h>
#include <hip/hip_bf16.h>

#define BIG 3.4e38f

// ---------- top-5 helpers ----------

// Merge two ascending sorted 5-lists, keep the 5 smallest in a[].
__device__ __forceinline__ void merge5(float a[5], const float* b) {
    float r[5];
#pragma unroll
    for (int k = 0; k < 5; ++k) {
        float best = BIG;
#pragma unroll
        for (int i = 0; i <= k + 1; ++i) {
            const int j = k + 1 - i;
            float va = (i == 0) ? -BIG : a[i - 1];
            float vb = (j == 0) ? -BIG : b[j - 1];
            best = fminf(best, fmaxf(va, vb));
        }
        r[k] = best;
    }
#pragma unroll
    for (int k = 0; k < 5; ++k) a[k] = r[k];
}

__device__ __forceinline__ void top5_insert(float m[5], float d) {
    if (d < m[4]) {
        m[4] = d;
#pragma unroll
        for (int k = 4; k > 0; --k) {
            float lo = fminf(m[k - 1], m[k]);
            float hi = fmaxf(m[k - 1], m[k]);
            m[k - 1] = lo;
            m[k] = hi;
        }
    }
}

// 5 smallest across the wave via iterative min-extract (~85 VALU ops vs
// 270 for the merge network). Exact w.r.t. duplicates: ballot+ffs masks
// exactly one instance per extraction. Result (sorted) in all lanes.
__device__ __forceinline__ void wave_top5_extract(float d, int lane,
                                                  float r[5]) {
#pragma unroll
    for (int k = 0; k < 5; ++k) {
        float v = d;
#pragma unroll
        for (int off = 32; off >= 1; off >>= 1)
            v = fminf(v, __shfl_xor(v, off, 64));
        r[k] = v;
        const unsigned long long ball = __ballot(d == v);
        const int src = (int)__ffsll(ball) - 1;
        if (lane == src) d = BIG;
    }
}

__device__ __forceinline__ void wave_merge_top5(float m[5]) {
#pragma unroll
    for (int off = 1; off < 64; off <<= 1) {
        float o[5];
#pragma unroll
        for (int k = 0; k < 5; ++k) o[k] = __shfl_xor(m[k], off, 64);
        merge5(m, o);
    }
}

__device__ __forceinline__ bool block_merge_top5(float m[5], float (*s_top)[5],
                                                 float r[5]) {
    const int wid = threadIdx.x >> 6;
    if ((threadIdx.x & 63) == 0) {
#pragma unroll
        for (int k = 0; k < 5; ++k) s_top[wid][k] = m[k];
    }
    __syncthreads();
    if (threadIdx.x == 0) {
#pragma unroll
        for (int k = 0; k < 5; ++k) r[k] = s_top[0][k];
        merge5(r, s_top[1]);
        merge5(r, s_top[2]);
        merge5(r, s_top[3]);
        return true;
    }
    return false;
}

// ---------- K1 v4: v3 geometry, NO occupancy hint (v3's launch_bounds
// (256,5) made the compiler cap VGPRs at 48 and spill acc[] to scratch:
// WRITE_SIZE 252KB -> 230MB, dur 55 -> 139us. LDS 31.7KB is the intended
// occupancy limiter at 5 blocks/CU; registers must stay unconstrained.) ----
// Blocks [0,1012): scale-0. Block = (h, col-quarter of 64 positions).
//   Lane = cq*16+pp: 4 channel-quarters x 16 positions per wave; wave wv
//   covers positions wv*16+pp. Per-position partials combine via
//   shfl_xor(16/32) — no LDS exchange, no cross-wave sync in main path.
//   Target table tl is skewed +cq*4 floats so the 4 concurrent b128
//   broadcast groups hit disjoint bank quads (else 4-way conflict).
// Blocks [1012,1076): scale-1 (C=128, ps=1), full dist + block top-5.
__global__ __launch_bounds__(256) void dist_all_kernel(
    const float* __restrict__ src0, const float* __restrict__ tgt0,
    const int* __restrict__ pos0, const float* __restrict__ src1,
    const float* __restrict__ tgt1, const int* __restrict__ pos1,
    float* __restrict__ p2a, float* __restrict__ p2b) {
    __shared__ float tl[7696];        // skewed: t*768 + ch*12 + i*4 + j + cq*4
    __shared__ float s_top[4][10][5];  // per-wave per-target top5

    const int b = blockIdx.x;
    if (b < 1012) {
        // ---- scale 0: C=64, H=W=256, ps=3 ----
        const int h = b >> 2;

        // Gather 10 target patches into skewed LDS layout (23KB of tgt0,
        // L2/L3-resident across the 1012 blocks).
        for (int t = 0; t < 10; ++t) {
            const int th = pos0[2 * t], tw = pos0[2 * t + 1];
            for (int inner = threadIdx.x; inner < 576; inner += 256) {
                const int ch = inner / 9;
                const int rr = inner - ch * 9;
                const int i = rr / 3, j = rr - i * 3;
                tl[t * 768 + ch * 12 + i * 4 + j + ((ch >> 4) << 2)] =
                    tgt0[(size_t)ch * 65536 + (th + i) * 256 + (tw + j)];
            }
        }
        __syncthreads();

        const int lane = threadIdx.x & 63;
        const int wv = threadIdx.x >> 6;  // wave: positions wv*16+pp
        const int pp = lane & 15;
        const int cq = lane >> 4;         // channel quarter
        const int wg = ((b & 3) << 6) + wv * 16 + pp;  // global w
        const int wp = (wg <= 252) ? wg : 252;         // clamp loads

        float acc[10];
#pragma unroll
        for (int t = 0; t < 10; ++t) acc[t] = 0.f;

        const float* sb = src0 + (size_t)(cq * 16) * 65536 + h * 256 + wp;
        const float* tb = tl + cq * 196;  // cq*192 (channels) + cq*4 (skew)
        for (int c = 0; c < 16; ++c) {
            const float* row = sb + (size_t)c * 65536;
            const float* tc = tb + c * 12;
#pragma unroll
            for (int i = 0; i < 3; ++i) {
                const float4 a = *(const float4*)(row + i * 256);
#pragma unroll
                for (int t = 0; t < 10; ++t) {
                    const float4 tv = *(const float4*)(tc + t * 768 + i * 4);
                    acc[t] += fabsf(a.x - tv.x) + fabsf(a.y - tv.y) +
                              fabsf(a.z - tv.z);
                }
            }
        }

        // Combine the 4 channel-quarters (lanes pp, pp+16, pp+32, pp+48).
#pragma unroll
        for (int t = 0; t < 10; ++t) {
            float d = acc[t];
            d += __shfl_xor(d, 16, 64);
            d += __shfl_xor(d, 32, 64);
            acc[t] = d;  // full distance in every lane of the pp-group
        }
        const bool valid = (cq == 0) && (wg < 253);

        // Per-target: wave top-5 of its 16 positions (others masked BIG).
#pragma unroll
        for (int t = 0; t < 10; ++t) {
            float r[5];
            wave_top5_extract(valid ? acc[t] : BIG, lane, r);
            if (lane == 0) {
#pragma unroll
                for (int k = 0; k < 5; ++k) s_top[wv][t][k] = r[k];
            }
        }
        __syncthreads();
        // Block merge: thread t merges the 4 wave lists for target t.
        if (threadIdx.x < 10) {
            const int t = threadIdx.x;
            float r[5];
#pragma unroll
            for (int k = 0; k < 5; ++k) r[k] = s_top[0][t][k];
            merge5(r, s_top[1][t]);
            merge5(r, s_top[2][t]);
            merge5(r, s_top[3][t]);
            float* dst = p2a + (t * 1012 + b) * 5;
#pragma unroll
            for (int k = 0; k < 5; ++k) dst[k] = r[k];
        }
    } else {
        // ---- scale 1: C=128, H=W=128, ps=1 ----
        const int bb = b - 1012;
        for (int idx = threadIdx.x; idx < 640; idx += 256) {
            const int t = idx >> 7, cc = idx & 127;
            tl[idx] =
                tgt1[(size_t)cc * 16384 + pos1[2 * t] * 128 + pos1[2 * t + 1]];
        }
        __syncthreads();

        const int w = threadIdx.x & 127;
        const int h1 = bb * 2 + (threadIdx.x >> 7);  // 0..127
        float acc[5] = {0.f, 0.f, 0.f, 0.f, 0.f};
        const float* sp = src1 + h1 * 128 + w;
        for (int cc = 0; cc < 128; ++cc) {
            const float v = sp[(size_t)cc * 16384];
#pragma unroll
            for (int t = 0; t < 5; ++t) acc[t] += fabsf(v - tl[t * 128 + cc]);
        }
        const int lane = threadIdx.x & 63;
        const int wv = threadIdx.x >> 6;
        const bool valid = (h1 < 127) && (w < 127);
#pragma unroll
        for (int t = 0; t < 5; ++t) {
            float r[5];
            wave_top5_extract(valid ? acc[t] : BIG, lane, r);
            if (lane == 0) {
#pragma unroll
                for (int k = 0; k < 5; ++k) s_top[wv][t][k] = r[k];
            }
        }
        __syncthreads();
        if (threadIdx.x < 5) {
            const int t = threadIdx.x;
            float r[5];
#pragma unroll
            for (int k = 0; k < 5; ++k) r[k] = s_top[0][t][k];
            merge5(r, s_top[1][t]);
            merge5(r, s_top[2][t]);
            merge5(r, s_top[3][t]);
            float* dst = p2b + (t * 64 + bb) * 5;
#pragma unroll
            for (int k = 0; k < 5; ++k) dst[k] = r[k];
        }
    }
}

// ---------- K3: parallel-over-targets final merge + scalar write --------
// Output word: high16 = f32 bits, low16 = RNE bf16 bits (dtype-proof).
__global__ __launch_bounds__(256) void final_merge_kernel(
    const float* __restrict__ p2a, int na,
    const float* __restrict__ p2b, int nb,
    unsigned int* __restrict__ out) {
    __shared__ float s_sum[15];
    const int lane = threadIdx.x & 63;
    const int wv = threadIdx.x >> 6;
#pragma unroll
    for (int rt = 0; rt < 4; ++rt) {
        const int t = wv * 4 + rt;
        if (t < 15) {
            const float* base = (t < 10) ? p2a + t * na : p2b + (t - 10) * nb;
            const int n = (t < 10) ? na : nb;
            const float scale =
                (t < 10) ? 1.f / (576.f * 5.f) : 1.f / (128.f * 5.f);
            float m[5] = {BIG, BIG, BIG, BIG, BIG};
            for (int b0 = 0; b0 < n; b0 += 256) {
                float v[4];
#pragma unroll
                for (int j = 0; j < 4; ++j) {
                    const int idx = b0 + j * 64 + lane;
                    v[j] = (idx < n) ? base[idx] : BIG;
                }
#pragma unroll
                for (int j = 0; j < 4; ++j) top5_insert(m, v[j]);
            }
            wave_merge_top5(m);
            if (lane == 0)
                s_sum[t] = (m[0] + m[1] + m[2] + m[3] + m[4]) * scale;
        }
    }
    __syncthreads();
    if (threadIdx.x == 0) {
        float total = 0.f;
#pragma unroll
        for (int t = 0; t < 15; ++t) total += s_sum[t];
        union { float f; unsigned int i; } uf;
        uf.f = total * 0.1f;
        unsigned int bf = (uf.i + 0x7FFFu + ((uf.i >> 16) & 1u)) >> 16;
        out[0] = (uf.i & 0xFFFF0000u) | (bf & 0xFFFFu);
    }
}

// ---------- fallback (round-2 proven path, tiny ws) ----------
template <int C, int H, int PS, int WM>
__global__ __launch_bounds__(256) void dist_top5_kernel(
    const float* __restrict__ src, const float* __restrict__ tgt,
    const int* __restrict__ pos, float* __restrict__ part) {
    constexpr int W = H;
    constexpr int K = C * PS * PS;
    constexpr int P = WM * WM;
    __shared__ float tlv[K];
    __shared__ float s_top[4][5];
    const int t = blockIdx.y;
    const int th = pos[2 * t], tw = pos[2 * t + 1];
    for (int idx = threadIdx.x; idx < K; idx += 256) {
        int c = idx / (PS * PS);
        int rem = idx - c * PS * PS;
        int i = rem / PS, j = rem - i * PS;
        tlv[idx] = tgt[(c * H + th + i) * W + tw + j];
    }
    __syncthreads();
    const int p = blockIdx.x * 256 + threadIdx.x;
    float d = BIG;
    if (p < P) {
        const int h = p / WM, w = p - h * WM;
        float acc = 0.f;
        for (int c = 0; c < C; ++c)
#pragma unroll
            for (int i = 0; i < PS; ++i) {
                const float* r = src + (c * H + h + i) * W + w;
                const float* tr = &tlv[(c * PS + i) * PS];
#pragma unroll
                for (int j = 0; j < PS; ++j) acc += fabsf(r[j] - tr[j]);
            }
        d = acc;
    }
    float m[5] = {d, BIG, BIG, BIG, BIG};
    wave_merge_top5(m);
    float r[5];
    if (block_merge_top5(m, s_top, r)) {
        float* dst = part + (t * gridDim.x + blockIdx.x) * 5;
#pragma unroll
        for (int k = 0; k < 5; ++k) dst[k] = r[k];
    }
}

extern "C" void kernel_launch(void* const* d_in, const int* in_sizes, int n_in,
                              void* d_out, int out_size, void* d_ws, size_t ws_size,
                              hipStream_t stream) {
    const float* src0 = (const float*)d_in[0];  // [1,64,256,256] f32
    const float* tgt0 = (const float*)d_in[1];
    const float* src1 = (const float*)d_in[2];  // [1,128,128,128] f32
    const float* tgt1 = (const float*)d_in[3];
    const int* pos0 = (const int*)d_in[4];      // [10,2]
    const int* pos1 = (const int*)d_in[5];      // [5,2]
    unsigned int* out = (unsigned int*)d_out;

    constexpr size_t NP2A = 10 * 1012 * 5;  // 50600
    constexpr size_t NP2B = 5 * 64 * 5;     // 1600
    const size_t need = (NP2A + NP2B) * 4;  // ~209 KB

    if (ws_size >= need) {
        float* p2a = (float*)d_ws;
        float* p2b = p2a + NP2A;

        // K1: scale-0 (1012 blocks) + scale-1 (64 blocks), all co-resident.
        dist_all_kernel<<<dim3(1076), 256, 0, stream>>>(
            src0, tgt0, pos0, src1, tgt1, pos1, p2a, p2b);
        // K3: final merge (10 x 5060 values + 5 x 320 values).
        final_merge_kernel<<<dim3(1), 256, 0, stream>>>(
            p2a, 1012 * 5, p2b, 320, out);
    } else {
        // Fallback: round-2 proven path (~57KB of ws).
        float* part0 = (float*)d_ws;
        float* part1 = part0 + 10 * 251 * 5;
        dist_top5_kernel<64, 256, 3, 253>
            <<<dim3(251, 10), 256, 0, stream>>>(src0, tgt0, pos0, part0);
        dist_top5_kernel<128, 128, 1, 127>
            <<<dim3(64, 5), 256, 0, stream>>>(src1, tgt1, pos1, part1);
        final_merge_kernel<<<dim3(1), 256, 0, stream>>>(part0, 1255, part1, 320, out);
    }
}

// Round 5
// 171.271 us; speedup vs baseline: 1.4888x; 1.2172x over previous
//
#include <hip/hip_runtime.h>
#include <hip/hip_bf16.h>

#define BIG 3.4e38f

// ---------- top-5 helpers ----------

// Merge two ascending sorted 5-lists, keep the 5 smallest in a[].
__device__ __forceinline__ void merge5(float a[5], const float* b) {
    float r[5];
#pragma unroll
    for (int k = 0; k < 5; ++k) {
        float best = BIG;
#pragma unroll
        for (int i = 0; i <= k + 1; ++i) {
            const int j = k + 1 - i;
            float va = (i == 0) ? -BIG : a[i - 1];
            float vb = (j == 0) ? -BIG : b[j - 1];
            best = fminf(best, fmaxf(va, vb));
        }
        r[k] = best;
    }
#pragma unroll
    for (int k = 0; k < 5; ++k) a[k] = r[k];
}

__device__ __forceinline__ void top5_insert(float m[5], float d) {
    if (d < m[4]) {
        m[4] = d;
#pragma unroll
        for (int k = 4; k > 0; --k) {
            float lo = fminf(m[k - 1], m[k]);
            float hi = fmaxf(m[k - 1], m[k]);
            m[k - 1] = lo;
            m[k] = hi;
        }
    }
}

// 5 smallest across the wave via iterative min-extract. Exact w.r.t.
// duplicates: ballot+ffs masks exactly one instance per extraction.
__device__ __forceinline__ void wave_top5_extract(float d, int lane,
                                                  float r[5]) {
#pragma unroll
    for (int k = 0; k < 5; ++k) {
        float v = d;
#pragma unroll
        for (int off = 32; off >= 1; off >>= 1)
            v = fminf(v, __shfl_xor(v, off, 64));
        r[k] = v;
        const unsigned long long ball = __ballot(d == v);
        const int src = (int)__ffsll(ball) - 1;
        if (lane == src) d = BIG;
    }
}

__device__ __forceinline__ void wave_merge_top5(float m[5]) {
#pragma unroll
    for (int off = 1; off < 64; off <<= 1) {
        float o[5];
#pragma unroll
        for (int k = 0; k < 5; ++k) o[k] = __shfl_xor(m[k], off, 64);
        merge5(m, o);
    }
}

__device__ __forceinline__ bool block_merge_top5(float m[5], float (*s_top)[5],
                                                 float r[5]) {
    const int wid = threadIdx.x >> 6;
    if ((threadIdx.x & 63) == 0) {
#pragma unroll
        for (int k = 0; k < 5; ++k) s_top[wid][k] = m[k];
    }
    __syncthreads();
    if (threadIdx.x == 0) {
#pragma unroll
        for (int k = 0; k < 5; ++k) r[k] = s_top[0][k];
        merge5(r, s_top[1]);
        merge5(r, s_top[2]);
        merge5(r, s_top[3]);
        return true;
    }
    return false;
}

// ---------- K0: pack target patches into streaming layout --------------
// tp0[c][t][i][4]: 64*10*3*4 = 7680 floats, 16B-aligned float4 per (c,t,i)
// (3 taps + pad). tp1[c][8]: t<5 valid. Enables s_load_dwordx4 in K1.
__global__ __launch_bounds__(256) void pack_kernel(
    const float* __restrict__ tgt0, const int* __restrict__ pos0,
    const float* __restrict__ tgt1, const int* __restrict__ pos1,
    float* __restrict__ tp0, float* __restrict__ tp1) {
    const int id = blockIdx.x * 256 + threadIdx.x;
    if (id < 1920) {  // c*30 + t*3 + i
        const int c = id / 30, rem = id - c * 30;
        const int t = rem / 3, i = rem - t * 3;
        const int th = pos0[2 * t], tw = pos0[2 * t + 1];
        const float* s = tgt0 + (size_t)c * 65536 + (th + i) * 256 + tw;
        float* d = tp0 + (size_t)id * 4;
        d[0] = s[0]; d[1] = s[1]; d[2] = s[2]; d[3] = 0.f;
    } else if (id < 2560) {
        const int j = id - 1920;
        const int c = j / 5, t = j - c * 5;
        tp1[c * 8 + t] =
            tgt1[(size_t)c * 16384 + pos1[2 * t] * 128 + pos1[2 * t + 1]];
    }
}

// ---------- K1 v5: SGPR-broadcast targets (no LDS in main loop) --------
// Round-4 diagnosis: 480 ds_read_b128/thread saturated the LDS pipe
// (per-CU LDS cycles ~2.7x VALU cycles -> VALUBusy 37%). Fix: channel
// split across WAVES (uniform) so tv addresses are wave-uniform ->
// s_load via scalar cache; inner loop is pure VALU (v_sub + v_add|abs|
// with SGPR operand). readfirstlane(wave-id) forces uniformity proof.
// Blocks [32,1044): scale-0. Block = 512 thr = 8 waves; wave q owns
//   channels 8q..8q+7; lane = 1 position (64-col quarter). Partials
//   combined via small LDS exchange ex[q][lane][12] (~30 ds ops/thread).
//   Wave g then owns target t=g (and g+8): reduce + wave top-5 -> p2a.
// Blocks [0,32): scale-1, 4 rows/block, SGPR tv likewise.
__global__ __launch_bounds__(512) void dist_all_kernel(
    const float* __restrict__ src0, const float* __restrict__ src1,
    const float* __restrict__ tp0, const float* __restrict__ tp1,
    float* __restrict__ p2a, float* __restrict__ p2b) {
    __shared__ float ex[8 * 64 * 12];  // 24576 B
    __shared__ float stp[8][5][5];     // scale-1 per-wave top5s
    const int tid = threadIdx.x;
    const int lane = tid & 63;
    const int wv = tid >> 6;
    const int q = __builtin_amdgcn_readfirstlane(wv);  // uniform wave id
    const int b = blockIdx.x;

    if (b >= 32) {
        // ---- scale 0: C=64, H=W=256, ps=3 ----
        const int bb = b - 32;
        const int h = bb >> 2;
        const int wbase = (bb & 3) << 6;
        const int w0 = wbase + lane;

        float acc[10];
#pragma unroll
        for (int t = 0; t < 10; ++t) acc[t] = 0.f;

        const float* sp = src0 + (size_t)(q * 8) * 65536 + h * 256 + w0;
        const float* tq = tp0 + q * 8 * 120;  // 120 floats per channel
        for (int c = 0; c < 8; ++c) {
            const float* row = sp + (size_t)c * 65536;
            const float* tvc = tq + c * 120;
#pragma unroll
            for (int i = 0; i < 3; ++i) {
                const float4 a = *(const float4*)(row + i * 256);
#pragma unroll
                for (int t = 0; t < 10; ++t) {
                    const float4 tv =
                        *(const float4*)(tvc + (t * 3 + i) * 4);  // s_load
                    acc[t] += fabsf(a.x - tv.x) + fabsf(a.y - tv.y) +
                              fabsf(a.z - tv.z);
                }
            }
        }

        // Exchange: ex[q][lane][12] (b128-aligned; t<10 valid).
        {
            float* e = ex + (q * 64 + lane) * 12;
            const float4 e0 = {acc[0], acc[1], acc[2], acc[3]};
            const float4 e1 = {acc[4], acc[5], acc[6], acc[7]};
            const float4 e2 = {acc[8], acc[9], 0.f, 0.f};
            *(float4*)(e + 0) = e0;
            *(float4*)(e + 4) = e1;
            *(float4*)(e + 8) = e2;
        }
        __syncthreads();

        // Wave g reduces target t=g (and g+8 for g<2) over 64 positions.
        const bool pvalid = (wbase + lane) < 253;
#pragma unroll
        for (int m = 0; m < 2; ++m) {
            const int t = q + m * 8;
            if (t < 10) {
                float s = 0.f;
#pragma unroll
                for (int qq = 0; qq < 8; ++qq)
                    s += ex[(qq * 64 + lane) * 12 + t];
                if (!pvalid) s = BIG;
                float r[5];
                wave_top5_extract(s, lane, r);
                if (lane == 0) {
                    float* dst = p2a + ((size_t)t * 1012 + bb) * 5;
#pragma unroll
                    for (int k = 0; k < 5; ++k) dst[k] = r[k];
                }
            }
        }
    } else {
        // ---- scale 1: C=128, H=W=128, ps=1; 4 rows per block ----
        const int w = tid & 127;
        const int h1 = b * 4 + (tid >> 7);
        float acc[5] = {0.f, 0.f, 0.f, 0.f, 0.f};
        const float* sp = src1 + h1 * 128 + w;
        for (int c = 0; c < 128; ++c) {
            const float v = sp[(size_t)c * 16384];
            const float4 t4 = *(const float4*)(tp1 + c * 8);  // s_load
            const float t5 = tp1[c * 8 + 4];
            acc[0] += fabsf(v - t4.x);
            acc[1] += fabsf(v - t4.y);
            acc[2] += fabsf(v - t4.z);
            acc[3] += fabsf(v - t4.w);
            acc[4] += fabsf(v - t5);
        }
        const bool valid = (w < 127) && (h1 < 127);
#pragma unroll
        for (int t = 0; t < 5; ++t) {
            float r[5];
            wave_top5_extract(valid ? acc[t] : BIG, lane, r);
            if (lane == 0) {
#pragma unroll
                for (int k = 0; k < 5; ++k) stp[wv][t][k] = r[k];
            }
        }
        __syncthreads();
        if (tid < 5) {
            float r[5];
#pragma unroll
            for (int k = 0; k < 5; ++k) r[k] = stp[0][tid][k];
#pragma unroll
            for (int wq = 1; wq < 8; ++wq) merge5(r, stp[wq][tid]);
            float* dst = p2b + (tid * 32 + b) * 5;
#pragma unroll
            for (int k = 0; k < 5; ++k) dst[k] = r[k];
        }
    }
}

// ---------- K3: parallel-over-targets final merge + scalar write --------
// Output word: high16 = f32 bits, low16 = RNE bf16 bits (dtype-proof).
__global__ __launch_bounds__(256) void final_merge_kernel(
    const float* __restrict__ p2a, int na,
    const float* __restrict__ p2b, int nb,
    unsigned int* __restrict__ out) {
    __shared__ float s_sum[15];
    const int lane = threadIdx.x & 63;
    const int wv = threadIdx.x >> 6;
#pragma unroll
    for (int rt = 0; rt < 4; ++rt) {
        const int t = wv * 4 + rt;
        if (t < 15) {
            const float* base = (t < 10) ? p2a + t * na : p2b + (t - 10) * nb;
            const int n = (t < 10) ? na : nb;
            const float scale =
                (t < 10) ? 1.f / (576.f * 5.f) : 1.f / (128.f * 5.f);
            float m[5] = {BIG, BIG, BIG, BIG, BIG};
            for (int b0 = 0; b0 < n; b0 += 256) {
                float v[4];
#pragma unroll
                for (int j = 0; j < 4; ++j) {
                    const int idx = b0 + j * 64 + lane;
                    v[j] = (idx < n) ? base[idx] : BIG;
                }
#pragma unroll
                for (int j = 0; j < 4; ++j) top5_insert(m, v[j]);
            }
            wave_merge_top5(m);
            if (lane == 0)
                s_sum[t] = (m[0] + m[1] + m[2] + m[3] + m[4]) * scale;
        }
    }
    __syncthreads();
    if (threadIdx.x == 0) {
        float total = 0.f;
#pragma unroll
        for (int t = 0; t < 15; ++t) total += s_sum[t];
        union { float f; unsigned int i; } uf;
        uf.f = total * 0.1f;
        unsigned int bf = (uf.i + 0x7FFFu + ((uf.i >> 16) & 1u)) >> 16;
        out[0] = (uf.i & 0xFFFF0000u) | (bf & 0xFFFFu);
    }
}

// ---------- fallback (round-2 proven path, tiny ws) ----------
template <int C, int H, int PS, int WM>
__global__ __launch_bounds__(256) void dist_top5_kernel(
    const float* __restrict__ src, const float* __restrict__ tgt,
    const int* __restrict__ pos, float* __restrict__ part) {
    constexpr int W = H;
    constexpr int K = C * PS * PS;
    constexpr int P = WM * WM;
    __shared__ float tlv[K];
    __shared__ float s_top[4][5];
    const int t = blockIdx.y;
    const int th = pos[2 * t], tw = pos[2 * t + 1];
    for (int idx = threadIdx.x; idx < K; idx += 256) {
        int c = idx / (PS * PS);
        int rem = idx - c * PS * PS;
        int i = rem / PS, j = rem - i * PS;
        tlv[idx] = tgt[(c * H + th + i) * W + tw + j];
    }
    __syncthreads();
    const int p = blockIdx.x * 256 + threadIdx.x;
    float d = BIG;
    if (p < P) {
        const int h = p / WM, w = p - h * WM;
        float acc = 0.f;
        for (int c = 0; c < C; ++c)
#pragma unroll
            for (int i = 0; i < PS; ++i) {
                const float* r = src + (c * H + h + i) * W + w;
                const float* tr = &tlv[(c * PS + i) * PS];
#pragma unroll
                for (int j = 0; j < PS; ++j) acc += fabsf(r[j] - tr[j]);
            }
        d = acc;
    }
    float m[5] = {d, BIG, BIG, BIG, BIG};
    wave_merge_top5(m);
    float r[5];
    if (block_merge_top5(m, s_top, r)) {
        float* dst = part + (t * gridDim.x + blockIdx.x) * 5;
#pragma unroll
        for (int k = 0; k < 5; ++k) dst[k] = r[k];
    }
}

extern "C" void kernel_launch(void* const* d_in, const int* in_sizes, int n_in,
                              void* d_out, int out_size, void* d_ws, size_t ws_size,
                              hipStream_t stream) {
    const float* src0 = (const float*)d_in[0];  // [1,64,256,256] f32
    const float* tgt0 = (const float*)d_in[1];
    const float* src1 = (const float*)d_in[2];  // [1,128,128,128] f32
    const float* tgt1 = (const float*)d_in[3];
    const int* pos0 = (const int*)d_in[4];      // [10,2]
    const int* pos1 = (const int*)d_in[5];      // [5,2]
    unsigned int* out = (unsigned int*)d_out;

    constexpr size_t NTP0 = 7680;
    constexpr size_t NTP1 = 1024;
    constexpr size_t NP2A = 10 * 1012 * 5;  // 50600
    constexpr size_t NP2B = 5 * 32 * 5;     // 800
    const size_t need = (NTP0 + NTP1 + NP2A + NP2B) * 4;  // ~240 KB

    if (ws_size >= need) {
        float* tp0 = (float*)d_ws;
        float* tp1 = tp0 + NTP0;
        float* p2a = tp1 + NTP1;
        float* p2b = p2a + NP2A;

        // K0: pack targets (2560 items).
        pack_kernel<<<dim3(10), 256, 0, stream>>>(tgt0, pos0, tgt1, pos1,
                                                  tp0, tp1);
        // K1: scale-1 (32 blocks) + scale-0 (1012 blocks), 512 threads.
        dist_all_kernel<<<dim3(1044), 512, 0, stream>>>(
            src0, src1, tp0, tp1, p2a, p2b);
        // K3: final merge (10 x 5060 values + 5 x 160 values).
        final_merge_kernel<<<dim3(1), 256, 0, stream>>>(
            p2a, 1012 * 5, p2b, 160, out);
    } else {
        // Fallback: round-2 proven path (~57KB of ws).
        float* part0 = (float*)d_ws;
        float* part1 = part0 + 10 * 251 * 5;
        dist_top5_kernel<64, 256, 3, 253>
            <<<dim3(251, 10), 256, 0, stream>>>(src0, tgt0, pos0, part0);
        dist_top5_kernel<128, 128, 1, 127>
            <<<dim3(64, 5), 256, 0, stream>>>(src1, tgt1, pos1, part1);
        final_merge_kernel<<<dim3(1), 256, 0, stream>>>(part0, 1255, part1, 320, out);
    }
}